// Round 1
// baseline (127.853 us; speedup 1.0000x reference)
//
#include <hip/hip_runtime.h>
#include <hip/hip_bf16.h>

#define NN 8192
#define F 64
#define ALPHA 0.2f

typedef __attribute__((ext_vector_type(8))) short short8;
typedef __attribute__((ext_vector_type(4))) float f32x4;

__device__ __forceinline__ short f2bf(float x) {
    union { float f; unsigned u; } v; v.f = x;
    unsigned r = v.u + 0x7FFF + ((v.u >> 16) & 1);
    return (short)(r >> 16);
}

// Kernel A: Wh = h @ W^T (fp32), store WhT (bf16, transposed 64 x 8192),
// src = Wh@a1, dst = Wh@a2. One wave per row.
__global__ __launch_bounds__(256) void k_prep(const float* __restrict__ h,
        const float* __restrict__ W, const float* __restrict__ a,
        short* __restrict__ WhT, float* __restrict__ src, float* __restrict__ dst) {
    __shared__ float Wl[F][F + 1];
    __shared__ short shT[F][4];
    int tid = threadIdx.x;
    for (int m = 0; m < 4; ++m) {
        int idx = m * 1024 + tid * 4;
        float4 v = *(const float4*)&W[idx];
        int row = idx >> 6, col = idx & 63;
        Wl[row][col] = v.x; Wl[row][col + 1] = v.y;
        Wl[row][col + 2] = v.z; Wl[row][col + 3] = v.w;
    }
    __syncthreads();
    int w = tid >> 6, lane = tid & 63;
    int i = blockIdx.x * 4 + w;
    const float* hrow = &h[(size_t)i * F];
    float wh = 0.f;
    #pragma unroll
    for (int k = 0; k < F; k += 4) {
        float4 hv = *(const float4*)&hrow[k];
        wh += hv.x * Wl[lane][k] + hv.y * Wl[lane][k + 1]
            + hv.z * Wl[lane][k + 2] + hv.w * Wl[lane][k + 3];
    }
    shT[lane][w] = f2bf(wh);
    float s1 = wh * a[lane];
    float s2 = wh * a[F + lane];
    #pragma unroll
    for (int off = 32; off; off >>= 1) {
        s1 += __shfl_xor(s1, off);
        s2 += __shfl_xor(s2, off);
    }
    if (lane == 0) { src[i] = s1; dst[i] = s2; }
    __syncthreads();
    if (tid < F) {
        short4 v = make_short4(shT[tid][0], shT[tid][1], shT[tid][2], shT[tid][3]);
        *(short4*)&WhT[(size_t)tid * NN + blockIdx.x * 4] = v;
    }
}

// Kernel B: dmax = max_j dst[j]
__global__ void k_dmax(const float* __restrict__ dst, float* __restrict__ dmax) {
    __shared__ float red[4];
    int tid = threadIdx.x;
    float m = -1e30f;
    for (int j = tid; j < NN; j += 256) m = fmaxf(m, dst[j]);
    #pragma unroll
    for (int off = 32; off; off >>= 1) m = fmaxf(m, __shfl_xor(m, off));
    if ((tid & 63) == 0) red[tid >> 6] = m;
    __syncthreads();
    if (tid == 0)
        *dmax = fmaxf(fmaxf(red[0], red[1]), fmaxf(red[2], red[3]));
}

// Kernel C: fused masked-softmax attention with shared upper-bound max.
// Block = 4 waves, 64 rows; grid = 128 row-blocks x G column-groups.
// Unnormalized partials: Opart[g] (8192x64 f32), lpart[g] (8192 f32).
__global__ __launch_bounds__(256) void k_attn(const int* __restrict__ adj,
        const short* __restrict__ WhT, const float* __restrict__ src,
        const float* __restrict__ dst, const float* __restrict__ dmax,
        float* __restrict__ Opart, float* __restrict__ lpart, int G) {
    int rb = blockIdx.x / G;
    int g  = blockIdx.x % G;
    int w = threadIdx.x >> 6, lane = threadIdx.x & 63;
    int r = lane & 15, q = lane >> 4;
    int i = rb * 64 + w * 16 + r;          // A-fragment row
    int cols = NN / G;
    int jbase = g * cols;

    float srcv = src[i];
    float sM = srcv + *dmax;
    float Mi = fmaxf(sM, ALPHA * sM);      // upper bound of row max

    f32x4 acc0{}, acc1{}, acc2{}, acc3{};
    float lsum = 0.f;

    const size_t arow = (size_t)i << 13;   // adj row offset
    const int nsteps = cols / 32;

    for (int t = 0; t < nsteps; ++t) {
        int jk = jbase + t * 32 + q * 8;   // this lane's 8 k-columns
        const int4* ap = (const int4*)&adj[arow + jk];
        int4 a0 = ap[0], a1 = ap[1];
        const float4* dp = (const float4*)&dst[jk];
        float4 d0 = dp[0], d1 = dp[1];

        auto pelem = [&](float dv, int av) -> short {
            float s = srcv + dv;
            float lr = fmaxf(s, ALPHA * s);
            float pe = __expf(lr - Mi);
            pe = (av > 0) ? pe : 0.f;
            lsum += pe;
            return f2bf(pe);
        };
        short8 af;
        af[0] = pelem(d0.x, a0.x); af[1] = pelem(d0.y, a0.y);
        af[2] = pelem(d0.z, a0.z); af[3] = pelem(d0.w, a0.w);
        af[4] = pelem(d1.x, a1.x); af[5] = pelem(d1.y, a1.y);
        af[6] = pelem(d1.z, a1.z); af[7] = pelem(d1.w, a1.w);

        const short* wb = WhT + jk;
        short8 b0 = *(const short8*)(wb + (size_t)(r)      * NN);
        short8 b1 = *(const short8*)(wb + (size_t)(16 + r) * NN);
        short8 b2 = *(const short8*)(wb + (size_t)(32 + r) * NN);
        short8 b3 = *(const short8*)(wb + (size_t)(48 + r) * NN);

        acc0 = __builtin_amdgcn_mfma_f32_16x16x32_bf16(af, b0, acc0, 0, 0, 0);
        acc1 = __builtin_amdgcn_mfma_f32_16x16x32_bf16(af, b1, acc1, 0, 0, 0);
        acc2 = __builtin_amdgcn_mfma_f32_16x16x32_bf16(af, b2, acc2, 0, 0, 0);
        acc3 = __builtin_amdgcn_mfma_f32_16x16x32_bf16(af, b3, acc3, 0, 0, 0);
    }

    lsum += __shfl_xor(lsum, 16);
    lsum += __shfl_xor(lsum, 32);
    if (q == 0) lpart[(size_t)g * NN + i] = lsum;

    int ic = rb * 64 + w * 16 + q * 4;     // C-fragment rows
    size_t ob = (size_t)g * (size_t)(NN * F);
    #pragma unroll
    for (int reg = 0; reg < 4; ++reg) {
        size_t ro = ob + (size_t)(ic + reg) * F + r;
        Opart[ro]      = acc0[reg];
        Opart[ro + 16] = acc1[reg];
        Opart[ro + 32] = acc2[reg];
        Opart[ro + 48] = acc3[reg];
    }
}

// Kernel D: out = elu( (sum_g Opart) / (sum_g lpart) )
__global__ __launch_bounds__(256) void k_reduce(const float* __restrict__ Opart,
        const float* __restrict__ lpart, float* __restrict__ out, int G) {
    int idx = blockIdx.x * 256 + threadIdx.x;
    int i = idx >> 6;
    float o = 0.f, l = 0.f;
    for (int g = 0; g < G; ++g) {
        o += Opart[(size_t)g * (NN * F) + idx];
        l += lpart[(size_t)g * NN + i];
    }
    float hp = o / l;
    out[idx] = hp > 0.f ? hp : __expf(hp) - 1.f;
}

extern "C" void kernel_launch(void* const* d_in, const int* in_sizes, int n_in,
                              void* d_out, int out_size, void* d_ws, size_t ws_size,
                              hipStream_t stream) {
    const float* h  = (const float*)d_in[0];
    const int* adj  = (const int*)d_in[1];
    const float* W  = (const float*)d_in[2];
    const float* a  = (const float*)d_in[3];
    float* out = (float*)d_out;

    char* ws = (char*)d_ws;
    const size_t OFF_WHT  = 0;                            // 1 MB bf16 WhT
    const size_t OFF_SRC  = (1u << 20);
    const size_t OFF_DST  = OFF_SRC + (32u << 10);
    const size_t OFF_DMAX = OFF_DST + (32u << 10);
    const size_t OFF_LP   = OFF_DMAX + 256;
    const size_t OFF_OP   = OFF_LP + 8ull * NN * 4;       // lpart reserved for G<=8

    short* WhT  = (short*)(ws + OFF_WHT);
    float* src  = (float*)(ws + OFF_SRC);
    float* dst  = (float*)(ws + OFF_DST);
    float* dmax = (float*)(ws + OFF_DMAX);
    float* lpart = (float*)(ws + OFF_LP);
    float* Opart = (float*)(ws + OFF_OP);

    int G = 8;
    while (G > 1 && OFF_OP + (size_t)G * NN * F * 4 > ws_size) G >>= 1;

    k_prep<<<NN / 4, 256, 0, stream>>>(h, W, a, WhT, src, dst);
    k_dmax<<<1, 256, 0, stream>>>(dst, dmax);
    k_attn<<<(NN / 64) * G, 256, 0, stream>>>(adj, WhT, src, dst, dmax, Opart, lpart, G);
    k_reduce<<<(NN * F) / 256, 256, 0, stream>>>(Opart, lpart, out, G);
}

// Round 2
// 118.130 us; speedup vs baseline: 1.0823x; 1.0823x over previous
//
#include <hip/hip_runtime.h>
#include <hip/hip_bf16.h>

#define NN 8192
#define F 64
#define ALPHA 0.2f
#define L2E 1.44269504f

typedef __attribute__((ext_vector_type(8))) short short8;
typedef __attribute__((ext_vector_type(4))) float f32x4;

__device__ __forceinline__ short f2bf(float x) {
    union { float f; unsigned u; } v; v.f = x;
    unsigned r = v.u + 0x7FFF + ((v.u >> 16) & 1);
    return (short)(r >> 16);
}

// Kernel A: Wh = h @ W^T (fp32), store WhT (bf16, transposed 64 x 8192),
// src = Wh@a1, dst = Wh@a2. One wave per row.
__global__ __launch_bounds__(256) void k_prep(const float* __restrict__ h,
        const float* __restrict__ W, const float* __restrict__ a,
        short* __restrict__ WhT, float* __restrict__ src, float* __restrict__ dst) {
    __shared__ float Wl[F][F + 1];
    __shared__ short shT[F][4];
    int tid = threadIdx.x;
    for (int m = 0; m < 4; ++m) {
        int idx = m * 1024 + tid * 4;
        float4 v = *(const float4*)&W[idx];
        int row = idx >> 6, col = idx & 63;
        Wl[row][col] = v.x; Wl[row][col + 1] = v.y;
        Wl[row][col + 2] = v.z; Wl[row][col + 3] = v.w;
    }
    __syncthreads();
    int w = tid >> 6, lane = tid & 63;
    int i = blockIdx.x * 4 + w;
    const float* hrow = &h[(size_t)i * F];
    float wh = 0.f;
    #pragma unroll
    for (int k = 0; k < F; k += 4) {
        float4 hv = *(const float4*)&hrow[k];
        wh += hv.x * Wl[lane][k] + hv.y * Wl[lane][k + 1]
            + hv.z * Wl[lane][k + 2] + hv.w * Wl[lane][k + 3];
    }
    shT[lane][w] = f2bf(wh);
    float s1 = wh * a[lane];
    float s2 = wh * a[F + lane];
    #pragma unroll
    for (int off = 32; off; off >>= 1) {
        s1 += __shfl_xor(s1, off);
        s2 += __shfl_xor(s2, off);
    }
    if (lane == 0) { src[i] = s1; dst[i] = s2; }
    __syncthreads();
    if (tid < F) {
        short4 v = make_short4(shT[tid][0], shT[tid][1], shT[tid][2], shT[tid][3]);
        *(short4*)&WhT[(size_t)tid * NN + blockIdx.x * 4] = v;
    }
}

// Kernel B: dmax = max_j dst[j].  One 1024-thread block, 8 elems/thread.
__global__ __launch_bounds__(1024) void k_dmax(const float* __restrict__ dst,
                                               float* __restrict__ dmax) {
    __shared__ float red[16];
    int tid = threadIdx.x;
    const float4* p = (const float4*)&dst[tid * 8];
    float4 v0 = p[0], v1 = p[1];
    float m = fmaxf(fmaxf(fmaxf(v0.x, v0.y), fmaxf(v0.z, v0.w)),
                    fmaxf(fmaxf(v1.x, v1.y), fmaxf(v1.z, v1.w)));
    #pragma unroll
    for (int off = 32; off; off >>= 1) m = fmaxf(m, __shfl_xor(m, off));
    if ((tid & 63) == 0) red[tid >> 6] = m;
    __syncthreads();
    if (tid == 0) {
        float r = red[0];
        #pragma unroll
        for (int k = 1; k < 16; ++k) r = fmaxf(r, red[k]);
        *dmax = r;
    }
}

// Kernel C: fused masked-softmax attention with shared upper-bound max.
// Block = 4 waves, 64 rows; grid = 128 row-blocks x G column-groups.
// Distance-1 prefetch on the adj stream; row-sum via MFMA against ones.
__global__ __launch_bounds__(256, 4) void k_attn(const int* __restrict__ adj,
        const short* __restrict__ WhT, const float* __restrict__ src,
        const float* __restrict__ dst, const float* __restrict__ dmax,
        float* __restrict__ Opart, float* __restrict__ lpart, int G) {
    int rb = blockIdx.x / G;
    int g  = blockIdx.x % G;
    int w = threadIdx.x >> 6, lane = threadIdx.x & 63;
    int r = lane & 15, q = lane >> 4;
    int i = rb * 64 + w * 16 + r;          // A-fragment row
    int cols = NN / G;
    int jbase = g * cols;

    float srcv = src[i];
    float sM = srcv + *dmax;
    float Mi = fmaxf(sM, ALPHA * sM);      // upper bound of row max
    float nMiL = -Mi * L2E;

    f32x4 acc0{}, acc1{}, acc2{}, acc3{}, acc4{};
    short8 ones;
    #pragma unroll
    for (int k = 0; k < 8; ++k) ones[k] = (short)0x3F80;  // bf16 1.0

    const size_t arow = (size_t)i << 13;   // adj row offset (ints)
    const int nsteps = cols / 32;
    const int4* ap = (const int4*)(adj + arow + jbase + q * 8);

    int4 ca0 = ap[0];
    int4 ca1 = ap[1];

    for (int t = 0; t < nsteps; ++t) {
        int tn = (t + 1 < nsteps) ? t + 1 : 0;          // in-bounds dummy on last
        int4 na0 = ap[(size_t)tn * 8];
        int4 na1 = ap[(size_t)tn * 8 + 1];

        int jk = jbase + t * 32 + q * 8;
        const float4* dp = (const float4*)(dst + jk);
        float4 d0 = dp[0], d1 = dp[1];

        auto pelem = [&](float dv, int av) -> short {
            float s = srcv + dv;
            float lr = fmaxf(s, ALPHA * s);
            float e = __builtin_amdgcn_exp2f(fmaf(lr, L2E, nMiL));
            e = (av > 0) ? e : 0.f;
            return f2bf(e);
        };
        short8 af;
        af[0] = pelem(d0.x, ca0.x); af[1] = pelem(d0.y, ca0.y);
        af[2] = pelem(d0.z, ca0.z); af[3] = pelem(d0.w, ca0.w);
        af[4] = pelem(d1.x, ca1.x); af[5] = pelem(d1.y, ca1.y);
        af[6] = pelem(d1.z, ca1.z); af[7] = pelem(d1.w, ca1.w);

        const short* wb = WhT + jk;
        short8 b0 = *(const short8*)(wb + (size_t)(r)      * NN);
        short8 b1 = *(const short8*)(wb + (size_t)(16 + r) * NN);
        short8 b2 = *(const short8*)(wb + (size_t)(32 + r) * NN);
        short8 b3 = *(const short8*)(wb + (size_t)(48 + r) * NN);

        acc0 = __builtin_amdgcn_mfma_f32_16x16x32_bf16(af, b0, acc0, 0, 0, 0);
        acc1 = __builtin_amdgcn_mfma_f32_16x16x32_bf16(af, b1, acc1, 0, 0, 0);
        acc2 = __builtin_amdgcn_mfma_f32_16x16x32_bf16(af, b2, acc2, 0, 0, 0);
        acc3 = __builtin_amdgcn_mfma_f32_16x16x32_bf16(af, b3, acc3, 0, 0, 0);
        acc4 = __builtin_amdgcn_mfma_f32_16x16x32_bf16(af, ones, acc4, 0, 0, 0);

        ca0 = na0; ca1 = na1;
    }

    // acc4: every column holds the row-sum; rows = q*4 + reg (C layout).
    int ic = rb * 64 + w * 16 + q * 4;     // C-fragment rows
    if (r == 0) {
        #pragma unroll
        for (int reg = 0; reg < 4; ++reg)
            lpart[(size_t)g * NN + ic + reg] = acc4[reg];
    }

    size_t ob = (size_t)g * (size_t)(NN * F);
    #pragma unroll
    for (int reg = 0; reg < 4; ++reg) {
        size_t ro = ob + (size_t)(ic + reg) * F + r;
        Opart[ro]      = acc0[reg];
        Opart[ro + 16] = acc1[reg];
        Opart[ro + 32] = acc2[reg];
        Opart[ro + 48] = acc3[reg];
    }
}

// Kernel D: out = elu( (sum_g Opart) / (sum_g lpart) )
__global__ __launch_bounds__(256) void k_reduce(const float* __restrict__ Opart,
        const float* __restrict__ lpart, float* __restrict__ out, int G) {
    int idx = blockIdx.x * 256 + threadIdx.x;
    int i = idx >> 6;
    float o = 0.f, l = 0.f;
    for (int g = 0; g < G; ++g) {
        o += Opart[(size_t)g * (NN * F) + idx];
        l += lpart[(size_t)g * NN + i];
    }
    float hp = o / l;
    out[idx] = hp > 0.f ? hp : __expf(hp) - 1.f;
}

extern "C" void kernel_launch(void* const* d_in, const int* in_sizes, int n_in,
                              void* d_out, int out_size, void* d_ws, size_t ws_size,
                              hipStream_t stream) {
    const float* h  = (const float*)d_in[0];
    const int* adj  = (const int*)d_in[1];
    const float* W  = (const float*)d_in[2];
    const float* a  = (const float*)d_in[3];
    float* out = (float*)d_out;

    char* ws = (char*)d_ws;
    const size_t OFF_WHT  = 0;                            // 1 MB bf16 WhT
    const size_t OFF_SRC  = (1u << 20);
    const size_t OFF_DST  = OFF_SRC + (32u << 10);
    const size_t OFF_DMAX = OFF_DST + (32u << 10);
    const size_t OFF_LP   = OFF_DMAX + 256;
    const size_t OFF_OP   = OFF_LP + 8ull * NN * 4;       // lpart reserved for G<=8

    short* WhT  = (short*)(ws + OFF_WHT);
    float* src  = (float*)(ws + OFF_SRC);
    float* dst  = (float*)(ws + OFF_DST);
    float* dmax = (float*)(ws + OFF_DMAX);
    float* lpart = (float*)(ws + OFF_LP);
    float* Opart = (float*)(ws + OFF_OP);

    int G = 8;
    while (G > 1 && OFF_OP + (size_t)G * NN * F * 4 > ws_size) G >>= 1;

    k_prep<<<NN / 4, 256, 0, stream>>>(h, W, a, WhT, src, dst);
    k_dmax<<<1, 1024, 0, stream>>>(dst, dmax);
    k_attn<<<(NN / 64) * G, 256, 0, stream>>>(adj, WhT, src, dst, dmax, Opart, lpart, G);
    k_reduce<<<(NN * F) / 256, 256, 0, stream>>>(Opart, lpart, out, G);
}